// Round 7
// baseline (202.891 us; speedup 1.0000x reference)
//
#include <hip/hip_runtime.h>

// GWRouter: x = mean(wm_state [4,4096,2048] f32); sim[e] = -(proto[e]-x)^2;
// probs = softmax(sim); top-2; mask; EMA usage update; balance loss.
// Outputs flat f32: mask[0:16), probs[16:32), balance_loss[32],
// new_usage_ema[33:49), topk_idx[49:51).
//
// Ledger: harness reset floor ~135-140us; controllable reduce ~60us at
// ~2.2 TB/s effective. R1/R5/R6 (three different ILP structures) tie ->
// not ILP-bound. R7 probe: sc0 (L1-bypass) loads via inline asm, 16-deep
// vmcnt FIFO, staged s_waitcnt vmcnt(12/8/4/0) consumption (never a full
// drain until the end). Tests the per-CU L1/TCP miss-concurrency-cap
// hypothesis. Two-kernel atomic-free structure (R4 lesson) retained.

#define NUM_EXPERTS 16
#define RED_BLOCKS 2048
#define RED_THREADS 256
#define ITERS 16   // 2048*256 threads * 16 float4 * 4 = 33,554,432 floats

typedef float f32x4 __attribute__((ext_vector_type(4)));

__device__ __forceinline__ f32x4 ld_sc0(const f32x4* p) {
    f32x4 r;
    asm volatile("global_load_dwordx4 %0, %1, off sc0"
                 : "=v"(r) : "v"(p) : "memory");
    return r;
}

// Wait until at most N vector-memory ops outstanding, and tie the 4 values
// to the wait so their consumers cannot be scheduled above it.
#define VMWAIT4(N, a, b, c, d)                                              \
    asm volatile("s_waitcnt vmcnt(" #N ")"                                  \
                 : "+v"(a), "+v"(b), "+v"(c), "+v"(d) :: "memory")

__global__ __launch_bounds__(RED_THREADS)
void gw_reduce(const f32x4* __restrict__ x4, int n4,
               double* __restrict__ partials) {
    __shared__ double sdata[RED_THREADS / 64];

    const int tid = blockIdx.x * RED_THREADS + threadIdx.x;
    const int stride = RED_BLOCKS * RED_THREADS;  // 524,288 float4s

    f32x4 s0 = {0.f, 0.f, 0.f, 0.f};
    f32x4 s1 = {0.f, 0.f, 0.f, 0.f};
    f32x4 s2 = {0.f, 0.f, 0.f, 0.f};
    f32x4 s3 = {0.f, 0.f, 0.f, 0.f};

    if (n4 == ITERS * stride) {
        const f32x4* p = x4 + tid;
        // Issue all 16 loads back-to-back (volatile => program order, one
        // FIFO). 16 KB in flight per wave, L1 bypassed via sc0.
        f32x4 v0  = ld_sc0(p +  0 * stride);
        f32x4 v1  = ld_sc0(p +  1 * stride);
        f32x4 v2  = ld_sc0(p +  2 * stride);
        f32x4 v3  = ld_sc0(p +  3 * stride);
        f32x4 v4  = ld_sc0(p +  4 * stride);
        f32x4 v5  = ld_sc0(p +  5 * stride);
        f32x4 v6  = ld_sc0(p +  6 * stride);
        f32x4 v7  = ld_sc0(p +  7 * stride);
        f32x4 v8  = ld_sc0(p +  8 * stride);
        f32x4 v9  = ld_sc0(p +  9 * stride);
        f32x4 v10 = ld_sc0(p + 10 * stride);
        f32x4 v11 = ld_sc0(p + 11 * stride);
        f32x4 v12 = ld_sc0(p + 12 * stride);
        f32x4 v13 = ld_sc0(p + 13 * stride);
        f32x4 v14 = ld_sc0(p + 14 * stride);
        f32x4 v15 = ld_sc0(p + 15 * stride);
        // FIFO consumption with partial drains (never vmcnt(0) mid-stream).
        VMWAIT4(12, v0, v1, v2, v3);
        s0 = v0; s1 = v1; s2 = v2; s3 = v3;
        VMWAIT4(8, v4, v5, v6, v7);
        s0 += v4; s1 += v5; s2 += v6; s3 += v7;
        VMWAIT4(4, v8, v9, v10, v11);
        s0 += v8; s1 += v9; s2 += v10; s3 += v11;
        VMWAIT4(0, v12, v13, v14, v15);
        s0 += v12; s1 += v13; s2 += v14; s3 += v15;
    } else {
        for (int i = tid; i < n4; i += stride) s0 += x4[i];
    }

    f32x4 sv = (s0 + s1) + (s2 + s3);
    double acc = ((double)sv.x + (double)sv.y) + ((double)sv.z + (double)sv.w);
    #pragma unroll
    for (int off = 32; off > 0; off >>= 1)
        acc += __shfl_down(acc, off, 64);

    const int lane = threadIdx.x & 63;
    const int wave = threadIdx.x >> 6;
    if (lane == 0) sdata[wave] = acc;
    __syncthreads();
    if (threadIdx.x == 0)
        partials[blockIdx.x] = sdata[0] + sdata[1] + sdata[2] + sdata[3];
}

__global__ __launch_bounds__(RED_THREADS)
void gw_finalize(const double* __restrict__ partials,
                 const float* __restrict__ prototypes,
                 const float* __restrict__ usage_ema,
                 float* __restrict__ out,
                 long long n_total) {
    __shared__ double sdata[RED_THREADS / 64];

    double facc = 0.0;
    #pragma unroll
    for (int k = 0; k < RED_BLOCKS / RED_THREADS; ++k)
        facc += partials[threadIdx.x + k * RED_THREADS];
    #pragma unroll
    for (int off = 32; off > 0; off >>= 1)
        facc += __shfl_down(facc, off, 64);

    const int lane = threadIdx.x & 63;
    const int wave = threadIdx.x >> 6;
    if (lane == 0) sdata[wave] = facc;
    __syncthreads();

    if (threadIdx.x == 0) {
        const double total = sdata[0] + sdata[1] + sdata[2] + sdata[3];
        const float x = (float)(total / (double)n_total);

        float sim[NUM_EXPERTS];
        float m = -1e30f;
        #pragma unroll
        for (int e = 0; e < NUM_EXPERTS; ++e) {
            float d = prototypes[e] - x;
            sim[e] = -d * d;
            m = fmaxf(m, sim[e]);
        }
        float probs[NUM_EXPERTS];
        float s = 0.0f;
        #pragma unroll
        for (int e = 0; e < NUM_EXPERTS; ++e) {
            probs[e] = expf(sim[e] - m);
            s += probs[e];
        }
        const float inv_s = 1.0f / s;
        #pragma unroll
        for (int e = 0; e < NUM_EXPERTS; ++e) probs[e] *= inv_s;

        // top-2, lowest-index tie-break (matches jax.lax.top_k)
        int i0 = 0;
        #pragma unroll
        for (int e = 1; e < NUM_EXPERTS; ++e)
            if (probs[e] > probs[i0]) i0 = e;
        int i1 = -1;
        #pragma unroll
        for (int e = 0; e < NUM_EXPERTS; ++e) {
            if (e == i0) continue;
            if (i1 < 0 || probs[e] > probs[i1]) i1 = e;
        }

        const float alpha = 1.0f / 1000.0f;
        const float target = 1.0f / (float)NUM_EXPERTS;
        float bal = 0.0f;
        #pragma unroll
        for (int e = 0; e < NUM_EXPERTS; ++e) {
            float mk = (e == i0 || e == i1) ? 1.0f : 0.0f;
            float ne = (1.0f - alpha) * usage_ema[e] + alpha * mk;
            out[e]      = mk;       // mask
            out[16 + e] = probs[e]; // probs
            out[33 + e] = ne;       // new_usage_ema
            float dlt = ne - target;
            bal += dlt * dlt;
        }
        out[32] = (bal / (float)NUM_EXPERTS) * 1e-3f; // balance_loss
        out[49] = (float)i0;                          // topk_idx
        out[50] = (float)i1;
    }
}

extern "C" void kernel_launch(void* const* d_in, const int* in_sizes, int n_in,
                              void* d_out, int out_size, void* d_ws, size_t ws_size,
                              hipStream_t stream) {
    const f32x4* wm_state   = (const f32x4*)d_in[0];
    const float* prototypes = (const float*)d_in[1];
    const float* usage_ema  = (const float*)d_in[2];
    float* out = (float*)d_out;

    const long long n_total = (long long)in_sizes[0];
    const int n4 = (int)(n_total / 4);

    double* partials = (double*)d_ws;  // 2048 doubles = 16 KiB

    gw_reduce<<<RED_BLOCKS, RED_THREADS, 0, stream>>>(wm_state, n4, partials);
    gw_finalize<<<1, RED_THREADS, 0, stream>>>(partials, prototypes, usage_ema,
                                               out, n_total);
}